// Round 3
// baseline (348.103 us; speedup 1.0000x reference)
//
#include <hip/hip_runtime.h>

namespace {
constexpr int T = 512;
constexpr int BATCH = 512;
constexpr int D = 32;
constexpr int H = 64;
constexpr int THREADS = 256;  // 4 waves/row; 4 lanes per h-index (K-split x4)
}

__device__ __forceinline__ float fast_sigmoid(float x) {
    return 1.0f / (1.0f + __expf(-x));
}
__device__ __forceinline__ float fast_tanh(float x) {
    // 1 - 2/(e^{2x}+1); saturates correctly via inf/0 at extremes
    return 1.0f - 2.0f / (__expf(2.0f * x) + 1.0f);
}

__global__ __launch_bounds__(THREADS) void gru_fused_kernel(
    const float* __restrict__ x,
    const float* __restrict__ w_ih_f, const float* __restrict__ w_hh_f,
    const float* __restrict__ b_ih_f, const float* __restrict__ b_hh_f,
    const float* __restrict__ w_ih_b, const float* __restrict__ b_ih_b,
    const float* __restrict__ b_hh_b,
    const float* __restrict__ fc1_w, const float* __restrict__ fc1_b,
    const float* __restrict__ fc2_w, const float* __restrict__ fc2_b,
    float* __restrict__ out)
{
    const int b   = blockIdx.x;   // batch row
    const int tid = threadIdx.x;
    const int j   = tid >> 2;     // h-index 0..63 — owns gates r,z,n for this j
    const int q   = tid & 3;      // K-split quarter
    const int kh0 = q * 16;       // this lane's h-k range [kh0, kh0+16)
    const int kx0 = q * 8;        // this lane's x-k range [kx0, kx0+8)

    __shared__ float4 x_lds[T * D / 4];   // 64 KB: whole x row staged once
    __shared__ float  h_lds[2][H];        // double-buffered hidden state
    __shared__ float  last_lds[2 * H];

    // ---- per-lane weight slices in registers (72 floats) ----
    float wr[16], wz[16], wn[16], ur[8], uz[8], un[8];
    {
        const float4* pr = reinterpret_cast<const float4*>(w_hh_f + (size_t)j * H + kh0);
        const float4* pz = reinterpret_cast<const float4*>(w_hh_f + (size_t)(H + j) * H + kh0);
        const float4* pn = reinterpret_cast<const float4*>(w_hh_f + (size_t)(2 * H + j) * H + kh0);
        #pragma unroll
        for (int m = 0; m < 4; ++m) {
            float4 a = pr[m]; wr[4*m+0]=a.x; wr[4*m+1]=a.y; wr[4*m+2]=a.z; wr[4*m+3]=a.w;
            float4 c = pz[m]; wz[4*m+0]=c.x; wz[4*m+1]=c.y; wz[4*m+2]=c.z; wz[4*m+3]=c.w;
            float4 d = pn[m]; wn[4*m+0]=d.x; wn[4*m+1]=d.y; wn[4*m+2]=d.z; wn[4*m+3]=d.w;
        }
        const float4* qr = reinterpret_cast<const float4*>(w_ih_f + (size_t)j * D + kx0);
        const float4* qz = reinterpret_cast<const float4*>(w_ih_f + (size_t)(H + j) * D + kx0);
        const float4* qn = reinterpret_cast<const float4*>(w_ih_f + (size_t)(2 * H + j) * D + kx0);
        #pragma unroll
        for (int m = 0; m < 2; ++m) {
            float4 a = qr[m]; ur[4*m+0]=a.x; ur[4*m+1]=a.y; ur[4*m+2]=a.z; ur[4*m+3]=a.w;
            float4 c = qz[m]; uz[4*m+0]=c.x; uz[4*m+1]=c.y; uz[4*m+2]=c.z; uz[4*m+3]=c.w;
            float4 d = qn[m]; un[4*m+0]=d.x; un[4*m+1]=d.y; un[4*m+2]=d.z; un[4*m+3]=d.w;
        }
    }

    const float pre_r  = b_ih_f[j]         + b_hh_f[j];
    const float pre_z  = b_ih_f[H + j]     + b_hh_f[H + j];
    const float pre_nx = b_ih_f[2 * H + j];
    const float pre_nh = b_hh_f[2 * H + j];

    // ---- stage x row into LDS (coalesced float4) ----
    {
        const float4* xg = reinterpret_cast<const float4*>(x + (size_t)b * T * D);
        #pragma unroll 4
        for (int i = tid; i < T * D / 4; i += THREADS) x_lds[i] = xg[i];
    }
    if (tid < H) h_lds[0][tid] = 0.0f;
    __syncthreads();

    for (int t = 0; t < T; ++t) {
        const int cur = t & 1, nxt = cur ^ 1;

        // lane's slices (LDS broadcast within 16-lane groups)
        float xx[8];
        {
            const float4* xt4 = x_lds + t * (D / 4) + q * 2;
            float4 a = xt4[0], c = xt4[1];
            xx[0]=a.x; xx[1]=a.y; xx[2]=a.z; xx[3]=a.w;
            xx[4]=c.x; xx[5]=c.y; xx[6]=c.z; xx[7]=c.w;
        }
        float hh[16];
        {
            const float4* hp = reinterpret_cast<const float4*>(&h_lds[cur][kh0]);
            #pragma unroll
            for (int m = 0; m < 4; ++m) {
                float4 a = hp[m];
                hh[4*m+0]=a.x; hh[4*m+1]=a.y; hh[4*m+2]=a.z; hh[4*m+3]=a.w;
            }
        }
        const float hold = h_lds[cur][j];

        // 6 independent accumulator chains (r/z/n × h/x parts)
        float arh = 0.f, azh = 0.f, anh = 0.f;
        #pragma unroll
        for (int k = 0; k < 16; ++k) {
            arh = fmaf(wr[k], hh[k], arh);
            azh = fmaf(wz[k], hh[k], azh);
            anh = fmaf(wn[k], hh[k], anh);
        }
        float arx = 0.f, azx = 0.f, anx = 0.f;
        #pragma unroll
        for (int k = 0; k < 8; ++k) {
            arx = fmaf(ur[k], xx[k], arx);
            azx = fmaf(uz[k], xx[k], azx);
            anx = fmaf(un[k], xx[k], anx);
        }

        // combine K-split partials across the 4 lanes sharing j (intra-wave)
        float pr  = arh + arx;
        float pz  = azh + azx;
        float pnh = anh;
        float pnx = anx;
        pr  += __shfl_xor(pr, 1);  pr  += __shfl_xor(pr, 2);
        pz  += __shfl_xor(pz, 1);  pz  += __shfl_xor(pz, 2);
        pnh += __shfl_xor(pnh, 1); pnh += __shfl_xor(pnh, 2);
        pnx += __shfl_xor(pnx, 1); pnx += __shfl_xor(pnx, 2);

        // all gates lane-local: no r/z exchange needed
        const float r = fast_sigmoid(pr + pre_r);
        const float z = fast_sigmoid(pz + pre_z);
        const float n = fast_tanh(pnx + pre_nx + r * (pnh + pre_nh));
        const float hnew = n + z * (hold - n);   // (1-z)n + z*hold

        if (q == 0) h_lds[nxt][j] = hnew;
        __syncthreads();   // single barrier per step
    }

    // ---- epilogue ----
    const int wave = tid >> 6, lane = tid & 63;

    // forward final state (T even -> buffer 0)
    if (wave == 0) last_lds[lane] = h_lds[T & 1][lane];

    // backward direction: exactly ONE step from h0 = 0 on x[b][T-1][:]
    if (wave == 1) {
        const float* xT = reinterpret_cast<const float*>(x_lds) + (T - 1) * D;
        const int jj = lane;
        float xr = b_ih_b[jj];
        float xz = b_ih_b[H + jj];
        float xn = b_ih_b[2 * H + jj];
        #pragma unroll
        for (int k = 0; k < D; ++k) {
            const float xv = xT[k];
            xr = fmaf(w_ih_b[(size_t)jj * D + k],           xv, xr);
            xz = fmaf(w_ih_b[(size_t)(H + jj) * D + k],     xv, xz);
            xn = fmaf(w_ih_b[(size_t)(2 * H + jj) * D + k], xv, xn);
        }
        const float r = fast_sigmoid(xr + b_hh_b[jj]);
        const float z = fast_sigmoid(xz + b_hh_b[H + jj]);
        const float n = fast_tanh(xn + r * b_hh_b[2 * H + jj]);
        last_lds[H + jj] = (1.0f - z) * n;   // z*h0 = 0
    }
    __syncthreads();

    // head: h1 = leaky(fc1_w @ last + fc1_b); out = fc2_w @ h1 + fc2_b
    if (wave == 0) {
        float acc = fc1_b[lane];
        const float* w1 = fc1_w + (size_t)lane * (2 * H);
        #pragma unroll 8
        for (int c = 0; c < 2 * H; ++c) acc = fmaf(w1[c], last_lds[c], acc);
        acc = (acc >= 0.0f) ? acc : 0.2f * acc;
        float red = acc * fc2_w[lane];
        #pragma unroll
        for (int off = 32; off > 0; off >>= 1)
            red += __shfl_down(red, off);
        if (lane == 0) out[b] = red + fc2_b[0];
    }
}

extern "C" void kernel_launch(void* const* d_in, const int* in_sizes, int n_in,
                              void* d_out, int out_size, void* d_ws, size_t ws_size,
                              hipStream_t stream) {
    const float* x      = (const float*)d_in[0];
    const float* w_ih_f = (const float*)d_in[1];
    const float* w_hh_f = (const float*)d_in[2];
    const float* b_ih_f = (const float*)d_in[3];
    const float* b_hh_f = (const float*)d_in[4];
    const float* w_ih_b = (const float*)d_in[5];
    // d_in[6] = w_hh_b: unused (backward direction runs exactly one step from h0=0)
    const float* b_ih_b = (const float*)d_in[7];
    const float* b_hh_b = (const float*)d_in[8];
    const float* fc1_w  = (const float*)d_in[9];
    const float* fc1_b  = (const float*)d_in[10];
    const float* fc2_w  = (const float*)d_in[11];
    const float* fc2_b  = (const float*)d_in[12];
    float* out = (float*)d_out;

    gru_fused_kernel<<<BATCH, THREADS, 0, stream>>>(
        x, w_ih_f, w_hh_f, b_ih_f, b_hh_f,
        w_ih_b, b_ih_b, b_hh_b,
        fc1_w, fc1_b, fc2_w, fc2_b, out);
}